// Round 6
// baseline (1736.093 us; speedup 1.0000x reference)
//
#include <hip/hip_runtime.h>
#include <math.h>

#define N_NODES 100000
#define N_EDGES 640000
#define IN_DIM 64
#define HID 128
#define NGRAPH 128
#define SPLIT 4      // attention-scan blocks per graph
#define PSTR 132     // floats per partial record: [0]=M [1]=S [4..131]=R

typedef __bf16 bf16x2 __attribute__((ext_vector_type(2)));
typedef __bf16 bf16x4 __attribute__((ext_vector_type(4)));
typedef __bf16 bf16x8 __attribute__((ext_vector_type(8)));
typedef float f32x4 __attribute__((ext_vector_type(4)));

#define LDST 136  // bf16 elements per LDS row: 272 B, 16B-aligned, breaks pow2 stride

// fast transcendentals; inf-safe at both ends.
__device__ __forceinline__ float sigmoid_f(float z) {
  return __fdividef(1.f, 1.f + __expf(-z));
}
__device__ __forceinline__ float tanh_f(float z) {
  return 1.f - __fdividef(2.f, __expf(2.f * z) + 1.f);
}

// ---------------------------------------------------------------------------
// fma helper (used by k_input only)
// ---------------------------------------------------------------------------
__device__ __forceinline__ void fma44(const float4 A[4], const float4 B[4], float acc[4][4]) {
#pragma unroll
  for (int i2 = 0; i2 < 4; ++i2) {
    acc[i2][0] += A[i2].x*B[0].x + A[i2].y*B[1].x + A[i2].z*B[2].x + A[i2].w*B[3].x;
    acc[i2][1] += A[i2].x*B[0].y + A[i2].y*B[1].y + A[i2].z*B[2].y + A[i2].w*B[3].y;
    acc[i2][2] += A[i2].x*B[0].z + A[i2].y*B[1].z + A[i2].z*B[2].z + A[i2].w*B[3].z;
    acc[i2][3] += A[i2].x*B[0].w + A[i2].y*B[1].w + A[i2].z*B[2].w + A[i2].w*B[3].w;
  }
}

// ---------------------------------------------------------------------------
// Kernel 1: h = relu(x @ W_in.T + b_in)
// ---------------------------------------------------------------------------
__global__ __launch_bounds__(256) void k_input(const float* __restrict__ x,
                                               const float* __restrict__ W,
                                               const float* __restrict__ b,
                                               float* __restrict__ h) {
  __shared__ float wS[64][132];
  __shared__ float xS[32][68];
  int t = threadIdx.x;
  int nb = blockIdx.x * 32;
#pragma unroll
  for (int i = 0; i < 8; ++i) {
    int idx4 = i * 256 + t;
    int j = idx4 >> 4, kq = idx4 & 15;
    float4 v = ((const float4*)W)[j * 16 + kq];
    wS[4*kq+0][j] = v.x; wS[4*kq+1][j] = v.y; wS[4*kq+2][j] = v.z; wS[4*kq+3][j] = v.w;
  }
#pragma unroll
  for (int i = 0; i < 2; ++i) {
    int idx4 = i * 256 + t;
    int n = idx4 >> 4, kq = idx4 & 15;
    float4 v = ((const float4*)x)[(nb + n) * 16 + kq];
    *((float4*)&xS[n][4*kq]) = v;
  }
  __syncthreads();
  int bq = t & 31, a = t >> 5;
  float acc[4][4] = {};
#pragma unroll
  for (int kk4 = 0; kk4 < 16; ++kk4) {
    float4 A[4], B[4];
#pragma unroll
    for (int i2 = 0; i2 < 4; ++i2) A[i2] = *((const float4*)&xS[4*a+i2][4*kk4]);
#pragma unroll
    for (int c = 0; c < 4; ++c) B[c] = *((const float4*)&wS[4*kk4+c][4*bq]);
    fma44(A, B, acc);
  }
  float4 bb = ((const float4*)b)[bq];
  float ba[4] = {bb.x, bb.y, bb.z, bb.w};
#pragma unroll
  for (int i2 = 0; i2 < 4; ++i2) {
    float4 o;
    o.x = fmaxf(acc[i2][0] + ba[0], 0.f);
    o.y = fmaxf(acc[i2][1] + ba[1], 0.f);
    o.z = fmaxf(acc[i2][2] + ba[2], 0.f);
    o.w = fmaxf(acc[i2][3] + ba[3], 0.f);
    ((float4*)h)[(nb + 4*a + i2) * 32 + bq] = o;
  }
}

// ---------------------------------------------------------------------------
// CSR build: histogram -> scan -> fill
// ---------------------------------------------------------------------------
__global__ __launch_bounds__(256) void k_hist(const int* __restrict__ dst,
                                              int* __restrict__ deg) {
  int e = blockIdx.x * 256 + threadIdx.x;
  if (e < N_EDGES) atomicAdd(&deg[dst[e]], 1);
}

#define SCAN_CHUNK 4096
#define SCAN_NB 25

__global__ __launch_bounds__(256) void k_scan_part(const int* __restrict__ deg,
                                                   int* __restrict__ bsum) {
  __shared__ int red[256];
  int t = threadIdx.x, b = blockIdx.x;
  int base = b * SCAN_CHUNK + t * 16;
  int s = 0;
#pragma unroll
  for (int i = 0; i < 16; ++i) {
    int idx = base + i;
    if (idx < N_NODES) s += deg[idx];
  }
  red[t] = s;
  __syncthreads();
  for (int off = 128; off > 0; off >>= 1) {
    if (t < off) red[t] += red[t + off];
    __syncthreads();
  }
  if (t == 0) bsum[b] = red[0];
}

__global__ void k_scan_mid(const int* __restrict__ bsum, int* __restrict__ boff,
                           int* __restrict__ rowstart) {
  if (threadIdx.x == 0) {
    int run = 0;
    for (int i = 0; i < SCAN_NB; ++i) { boff[i] = run; run += bsum[i]; }
    rowstart[N_NODES] = run;
  }
}

__global__ __launch_bounds__(256) void k_scan_final(const int* __restrict__ deg,
                                                    const int* __restrict__ boff,
                                                    int* __restrict__ rowstart) {
  __shared__ int ts[256];
  int t = threadIdx.x, b = blockIdx.x;
  int base = b * SCAN_CHUNK + t * 16;
  int v[16];
  int s = 0;
#pragma unroll
  for (int i = 0; i < 16; ++i) {
    int idx = base + i;
    v[i] = (idx < N_NODES) ? deg[idx] : 0;
    s += v[i];
  }
  ts[t] = s;
  __syncthreads();
  for (int off = 1; off < 256; off <<= 1) {
    int add = (t >= off) ? ts[t - off] : 0;
    __syncthreads();
    ts[t] += add;
    __syncthreads();
  }
  int run = boff[b] + ts[t] - s;
#pragma unroll
  for (int i = 0; i < 16; ++i) {
    int idx = base + i;
    if (idx < N_NODES) rowstart[idx] = run;
    run += v[i];
  }
}

__global__ __launch_bounds__(256) void k_fill(const int* __restrict__ src,
                                              const int* __restrict__ dst,
                                              int* __restrict__ cursor,
                                              int* __restrict__ srcSorted) {
  int e = blockIdx.x * 256 + threadIdx.x;
  if (e >= N_EDGES) return;
  int d = dst[e];
  int p = atomicAdd(&cursor[d], 1);
  srcSorted[p] = src[e];
}

// ---------------------------------------------------------------------------
// One-time weight split fp32 -> bf16 (hi, lo). Layout preserved: [mat][j][k]
// ---------------------------------------------------------------------------
__global__ __launch_bounds__(256) void k_wsplit(const float* __restrict__ W0,
                                                const float* __restrict__ W1,
                                                const float* __restrict__ W2,
                                                const float* __restrict__ W3,
                                                __bf16* __restrict__ Whi,
                                                __bf16* __restrict__ Wlo) {
  int id = blockIdx.x * 256 + threadIdx.x;  // 65536 total
  int mat = id >> 14, idx = id & 16383;
  const float* W = (mat == 0) ? W0 : (mat == 1) ? W1 : (mat == 2) ? W2 : W3;
  float v = W[idx];
  __bf16 hi = (__bf16)v;
  Whi[id] = hi;
  Wlo[id] = (__bf16)(v - (float)hi);
}

// ---------------------------------------------------------------------------
// Fused aggregation + MGU update, MFMA split-bf16, double-buffered h.
// v10: v7 geometry (32 nodes/block, 4 blocks/CU, acc[2][2]) with an
// EDGE-PARALLEL gather: all 256 threads stream the block's contiguous CSR
// edge range; per (edge,lane) 4 strided dword loads + 4 LDS atomicAdd f32
// into a dense fp32 mAcc[32][128] (bank = lane -> 2-way max, free).
// Node id per edge via 5-step binary search over 33 cached rowstart bounds.
// All loads independent -> no dependent-chain rounds, no degree imbalance.
// mAcc aliases the mHi/mLo region (regs bridge the conversion across a
// barrier) so LDS stays 34,816 B -> 4 blocks/CU.
// ---------------------------------------------------------------------------
__global__ __launch_bounds__(256, 4) void k_mgu(float* __restrict__ hdst,
                                                const float* __restrict__ hsrc,
                                                const int* __restrict__ rowstart,
                                                const int* __restrict__ srcSorted,
                                                const __bf16* __restrict__ Whi,
                                                const __bf16* __restrict__ Wlo,
                                                const float* __restrict__ bfp,
                                                const float* __restrict__ bhp) {
  __shared__ __align__(16) unsigned char mArea[32 * LDST * 2 * 2];  // 17,408 B
  __shared__ __bf16 hHi[32 * LDST], hLo[32 * LDST];  // becomes g after f-gate
  __shared__ int bndS[33];
  __bf16* mHi = (__bf16*)mArea;                      // [32*LDST] bf16
  __bf16* mLo = (__bf16*)(mArea + 32 * LDST * 2);    // [32*LDST] bf16
  float*  mAcc = (float*)mArea;                      // [32][128] fp32 (aliased)

  const int t = threadIdx.x;
  const int nb = blockIdx.x * 32;

  if (t < 33) bndS[t] = rowstart[nb + t];

  // ---- zero fp32 m accumulator ----
#pragma unroll
  for (int i = 0; i < 4; ++i)
    ((float4*)mAcc)[i * 256 + t] = make_float4(0.f, 0.f, 0.f, 0.f);

  // ---- stage own 32 rows of h, split to bf16 hi/lo ----
#pragma unroll
  for (int i = 0; i < 4; ++i) {
    int idx4 = i * 256 + t;
    int n = idx4 >> 5, kq = idx4 & 31;
    float4 vh = ((const float4*)hsrc)[(nb + n) * 32 + kq];
    bf16x4 hh, hl;
    hh[0] = (__bf16)vh.x; hl[0] = (__bf16)(vh.x - (float)hh[0]);
    hh[1] = (__bf16)vh.y; hl[1] = (__bf16)(vh.y - (float)hh[1]);
    hh[2] = (__bf16)vh.z; hl[2] = (__bf16)(vh.z - (float)hh[2]);
    hh[3] = (__bf16)vh.w; hl[3] = (__bf16)(vh.w - (float)hh[3]);
    int e0 = n * LDST + 4 * kq;
    *(bf16x4*)&hHi[e0] = hh; *(bf16x4*)&hLo[e0] = hl;
  }
  __syncthreads();

  // ---- edge-parallel gather: mAcc[n][:] += h[src[e]][:] over block's edges ----
  {
    const int li = t & 31, eg = t >> 5;
    const int e0 = bndS[0], e1 = bndS[32];
    int e = e0 + eg;
    for (; e + 8 < e1; e += 16) {  // 2 edges per iteration, stride 8 over 8 slots
      int ea = e, eb = e + 8;
      int sa = srcSorted[ea], sb = srcSorted[eb];
      int loa = 0, hia = 32;
#pragma unroll
      for (int it = 0; it < 5; ++it) { int mid = (loa + hia) >> 1; if (bndS[mid] <= ea) loa = mid; else hia = mid; }
      int lob = 0, hib = 32;
#pragma unroll
      for (int it = 0; it < 5; ++it) { int mid = (lob + hib) >> 1; if (bndS[mid] <= eb) lob = mid; else hib = mid; }
      const float* pa = hsrc + sa * 128 + li;
      const float* pb = hsrc + sb * 128 + li;
      float a0 = pa[0], a1 = pa[32], a2 = pa[64], a3 = pa[96];
      float b0 = pb[0], b1 = pb[32], b2 = pb[64], b3 = pb[96];
      float* da = &mAcc[loa * 128 + li];
      float* db = &mAcc[lob * 128 + li];
      atomicAdd(da, a0); atomicAdd(da + 32, a1); atomicAdd(da + 64, a2); atomicAdd(da + 96, a3);
      atomicAdd(db, b0); atomicAdd(db + 32, b1); atomicAdd(db + 64, b2); atomicAdd(db + 96, b3);
    }
    if (e < e1) {
      int sa = srcSorted[e];
      int loa = 0, hia = 32;
#pragma unroll
      for (int it = 0; it < 5; ++it) { int mid = (loa + hia) >> 1; if (bndS[mid] <= e) loa = mid; else hia = mid; }
      const float* pa = hsrc + sa * 128 + li;
      float a0 = pa[0], a1 = pa[32], a2 = pa[64], a3 = pa[96];
      float* da = &mAcc[loa * 128 + li];
      atomicAdd(da, a0); atomicAdd(da + 32, a1); atomicAdd(da + 64, a2); atomicAdd(da + 96, a3);
    }
  }
  __syncthreads();

  // ---- convert mAcc fp32 -> mHi/mLo bf16 (aliased; regs bridge barrier) ----
  float4 cv[4];
#pragma unroll
  for (int i = 0; i < 4; ++i) {
    int idx4 = i * 256 + t;
    int n = idx4 >> 5, kq = idx4 & 31;
    cv[i] = ((const float4*)mAcc)[n * 32 + kq];
  }
  __syncthreads();
#pragma unroll
  for (int i = 0; i < 4; ++i) {
    int idx4 = i * 256 + t;
    int n = idx4 >> 5, kq = idx4 & 31;
    bf16x4 mh, ml;
    mh[0] = (__bf16)cv[i].x; ml[0] = (__bf16)(cv[i].x - (float)mh[0]);
    mh[1] = (__bf16)cv[i].y; ml[1] = (__bf16)(cv[i].y - (float)mh[1]);
    mh[2] = (__bf16)cv[i].z; ml[2] = (__bf16)(cv[i].z - (float)mh[2]);
    mh[3] = (__bf16)cv[i].w; ml[3] = (__bf16)(cv[i].w - (float)mh[3]);
    int ee = n * LDST + 4 * kq;
    *(bf16x4*)&mHi[ee] = mh; *(bf16x4*)&mLo[ee] = ml;
  }
  __syncthreads();

  const int w = t >> 6, l = t & 63;
  const int lj = l & 15, q = l >> 4;

  float bfj[2], bhj[2];
#pragma unroll
  for (int ct = 0; ct < 2; ++ct) {
    int j = (2 * w + ct) * 16 + lj;
    bfj[ct] = bfp[j];
    bhj[ct] = bhp[j];
  }

  f32x4 acc[2][2] = {};

  // ---- phase A: z_f = m@Wf.T + h@Uf.T ----
#pragma unroll
  for (int kc = 0; kc < 128; kc += 32) {
    bf16x8 bwh[2], bwl[2], buh[2], bul[2];
#pragma unroll
    for (int ct = 0; ct < 2; ++ct) {
      int off = ((2 * w + ct) * 16 + lj) * 128 + kc + q * 8;
      bwh[ct] = *(const bf16x8*)&Whi[off];
      bwl[ct] = *(const bf16x8*)&Wlo[off];
      buh[ct] = *(const bf16x8*)&Whi[16384 + off];
      bul[ct] = *(const bf16x8*)&Wlo[16384 + off];
    }
#pragma unroll
    for (int rt = 0; rt < 2; ++rt) {
      int e0 = (rt * 16 + lj) * LDST + kc + q * 8;
      bf16x8 amh = *(const bf16x8*)&mHi[e0];
      bf16x8 aml = *(const bf16x8*)&mLo[e0];
      bf16x8 ahh = *(const bf16x8*)&hHi[e0];
      bf16x8 ahl = *(const bf16x8*)&hLo[e0];
#pragma unroll
      for (int ct = 0; ct < 2; ++ct) {
        f32x4 a = acc[rt][ct];
        a = __builtin_amdgcn_mfma_f32_16x16x32_bf16(amh, bwh[ct], a, 0, 0, 0);
        a = __builtin_amdgcn_mfma_f32_16x16x32_bf16(amh, bwl[ct], a, 0, 0, 0);
        a = __builtin_amdgcn_mfma_f32_16x16x32_bf16(aml, bwh[ct], a, 0, 0, 0);
        a = __builtin_amdgcn_mfma_f32_16x16x32_bf16(ahh, buh[ct], a, 0, 0, 0);
        a = __builtin_amdgcn_mfma_f32_16x16x32_bf16(ahh, bul[ct], a, 0, 0, 0);
        a = __builtin_amdgcn_mfma_f32_16x16x32_bf16(ahl, buh[ct], a, 0, 0, 0);
        acc[rt][ct] = a;
      }
    }
  }

  // ---- transition: f = sigmoid(z_f + bf); g = f*h overwrites h tile ----
  __syncthreads();  // all phase-A reads of hHi/hLo complete
  float fv[2][2][4], hvv[2][2][4];
#pragma unroll
  for (int rt = 0; rt < 2; ++rt)
#pragma unroll
    for (int ct = 0; ct < 2; ++ct) {
      int j = (2 * w + ct) * 16 + lj;
#pragma unroll
      for (int r = 0; r < 4; ++r) {
        int nl = rt * 16 + q * 4 + r;
        float z = acc[rt][ct][r] + bfj[ct];
        float f = sigmoid_f(z);
        int he = nl * LDST + j;
        float hval = (float)hHi[he] + (float)hLo[he];
        float g = f * hval;
        __bf16 ghi = (__bf16)g;
        hHi[he] = ghi;
        hLo[he] = (__bf16)(g - (float)ghi);
        fv[rt][ct][r] = f;
        hvv[rt][ct][r] = hval;
        acc[rt][ct][r] = 0.f;
      }
    }
  __syncthreads();

  // ---- phase B: z_h = m@Wh.T + g@Uh.T ----
#pragma unroll
  for (int kc = 0; kc < 128; kc += 32) {
    bf16x8 bwh[2], bwl[2], buh[2], bul[2];
#pragma unroll
    for (int ct = 0; ct < 2; ++ct) {
      int off = ((2 * w + ct) * 16 + lj) * 128 + kc + q * 8;
      bwh[ct] = *(const bf16x8*)&Whi[2 * 16384 + off];
      bwl[ct] = *(const bf16x8*)&Wlo[2 * 16384 + off];
      buh[ct] = *(const bf16x8*)&Whi[3 * 16384 + off];
      bul[ct] = *(const bf16x8*)&Wlo[3 * 16384 + off];
    }
#pragma unroll
    for (int rt = 0; rt < 2; ++rt) {
      int e0 = (rt * 16 + lj) * LDST + kc + q * 8;
      bf16x8 amh = *(const bf16x8*)&mHi[e0];
      bf16x8 aml = *(const bf16x8*)&mLo[e0];
      bf16x8 agh = *(const bf16x8*)&hHi[e0];
      bf16x8 agl = *(const bf16x8*)&hLo[e0];
#pragma unroll
      for (int ct = 0; ct < 2; ++ct) {
        f32x4 a = acc[rt][ct];
        a = __builtin_amdgcn_mfma_f32_16x16x32_bf16(amh, bwh[ct], a, 0, 0, 0);
        a = __builtin_amdgcn_mfma_f32_16x16x32_bf16(amh, bwl[ct], a, 0, 0, 0);
        a = __builtin_amdgcn_mfma_f32_16x16x32_bf16(aml, bwh[ct], a, 0, 0, 0);
        a = __builtin_amdgcn_mfma_f32_16x16x32_bf16(agh, buh[ct], a, 0, 0, 0);
        a = __builtin_amdgcn_mfma_f32_16x16x32_bf16(agh, bul[ct], a, 0, 0, 0);
        a = __builtin_amdgcn_mfma_f32_16x16x32_bf16(agl, buh[ct], a, 0, 0, 0);
        acc[rt][ct] = a;
      }
    }
  }

  // ---- epilogue: h_new = (1-f)*h + f*tanh(z_h + bh), to hdst ----
#pragma unroll
  for (int rt = 0; rt < 2; ++rt)
#pragma unroll
    for (int ct = 0; ct < 2; ++ct) {
      int j = (2 * w + ct) * 16 + lj;
#pragma unroll
      for (int r = 0; r < 4; ++r) {
        int node = nb + rt * 16 + q * 4 + r;
        float T = tanh_f(acc[rt][ct][r] + bhj[ct]);
        float f = fv[rt][ct][r];
        float hn = (1.f - f) * hvv[rt][ct][r] + f * T;
        hdst[node * 128 + j] = hn;
      }
    }
}

// ---------------------------------------------------------------------------
// Set2Set, split pipeline.
// k_s2s_init: step-0 LSTM from zeros (gates = biases) -> q0, h, c per graph.
// ---------------------------------------------------------------------------
__global__ __launch_bounds__(128) void k_s2s_init(const float* __restrict__ b_ih,
                                                  const float* __restrict__ b_hh,
                                                  float* __restrict__ q_buf,
                                                  float* __restrict__ hc_buf) {
  int g = blockIdx.x, t = threadIdx.x;
  float gi = b_ih[t] + b_hh[t];
  float gf = b_ih[128 + t] + b_hh[128 + t];
  float gg = b_ih[256 + t] + b_hh[256 + t];
  float go = b_ih[384 + t] + b_hh[384 + t];
  float c = sigmoid_f(gi) * tanh_f(gg);        // c_prev = 0
  float hh = sigmoid_f(go) * tanh_f(c);
  q_buf[g * 128 + t] = hh;
  hc_buf[g * 256 + t] = hh;
  hc_buf[g * 256 + 128 + t] = c;
}

// ---------------------------------------------------------------------------
// k_s2s_scan: block (g,p) scans a disjoint quarter of graph g with online
// softmax (32 streams x 32 lanes), writes unnormalized partial {M,S,R[128]}.
// ---------------------------------------------------------------------------
__global__ __launch_bounds__(1024, 8) void k_s2s_scan(const float* __restrict__ h,
                                                      const int* __restrict__ batch,
                                                      const float* __restrict__ q_buf,
                                                      float* __restrict__ partials) {
  const int b = blockIdx.x;
  const int g = b >> 2, p = b & (SPLIT - 1);
  const int t = threadIdx.x;
  const int w = t >> 6, l = t & 63;
  const int half = l >> 5, li = l & 31;
  const int hw = 2 * w + half;           // stream id 0..31
  __shared__ float redM[32], redS[32], scl[32];
  __shared__ float rPart[32][132];
  __shared__ float sMS[2];
  __shared__ int bnd[2];

  if (t < 2) {
    int tgt = g + t;
    int lo = 0, hi = N_NODES;
    while (lo < hi) { int mid = (lo + hi) >> 1; if (batch[mid] < tgt) lo = mid + 1; else hi = mid; }
    bnd[t] = lo;
  }
  __syncthreads();
  const int s0 = bnd[0], s1 = bnd[1];
  const int len = s1 - s0;
  const int ps = s0 + (len * p) / SPLIT;
  const int pe = s0 + (len * (p + 1)) / SPLIT;

  // per-lane query slice
  float4 qv = ((const float4*)(q_buf + g * 128))[li];
  const float q0 = qv.x, q1 = qv.y, q2 = qv.z, q3 = qv.w;

  float mw = -INFINITY, sw = 0.f;
  float4 racc = {0.f, 0.f, 0.f, 0.f};
  const float4* h4 = (const float4*)h;
  int n = ps + hw;
  for (; n + 32 < pe; n += 64) {
    float4 hv0 = h4[n * 32 + li];
    float4 hv1 = h4[(n + 32) * 32 + li];
    float v0 = hv0.x * q0 + hv0.y * q1 + hv0.z * q2 + hv0.w * q3;
    float v1 = hv1.x * q0 + hv1.y * q1 + hv1.z * q2 + hv1.w * q3;
#pragma unroll
    for (int o = 16; o > 0; o >>= 1) {
      v0 += __shfl_xor(v0, o, 64);
      v1 += __shfl_xor(v1, o, 64);
    }
    float nm = fmaxf(mw, fmaxf(v0, v1));
    float sc = __expf(mw - nm);
    float w0 = __expf(v0 - nm);
    float w1 = __expf(v1 - nm);
    sw = sw * sc + w0 + w1;
    racc.x = racc.x * sc + w0 * hv0.x + w1 * hv1.x;
    racc.y = racc.y * sc + w0 * hv0.y + w1 * hv1.y;
    racc.z = racc.z * sc + w0 * hv0.z + w1 * hv1.z;
    racc.w = racc.w * sc + w0 * hv0.w + w1 * hv1.w;
    mw = nm;
  }
  for (; n < pe; n += 32) {
    float4 hv = h4[n * 32 + li];
    float v = hv.x * q0 + hv.y * q1 + hv.z * q2 + hv.w * q3;
#pragma unroll
    for (int o = 16; o > 0; o >>= 1) v += __shfl_xor(v, o, 64);
    float nm = fmaxf(mw, v);
    float sc = __expf(mw - nm);
    float wg = __expf(v - nm);
    sw = sw * sc + wg;
    racc.x = racc.x * sc + wg * hv.x;
    racc.y = racc.y * sc + wg * hv.y;
    racc.z = racc.z * sc + wg * hv.z;
    racc.w = racc.w * sc + wg * hv.w;
    mw = nm;
  }
  if (li == 0) { redM[hw] = mw; redS[hw] = sw; }
  *(float4*)&rPart[hw][4 * li] = racc;
  __syncthreads();
  if (t == 0) {
    float M = -INFINITY;
    for (int i = 0; i < 32; ++i) M = fmaxf(M, redM[i]);
    float S = 0.f;
    for (int i = 0; i < 32; ++i) {
      float s_ = (redM[i] > -INFINITY && M > -INFINITY) ? __expf(redM[i] - M) : 0.f;
      scl[i] = s_;
      S += redS[i] * s_;
    }
    sMS[0] = M; sMS[1] = S;
  }
  __syncthreads();
  float* P = partials + (g * SPLIT + p) * PSTR;
  if (t == 0) { P[0] = sMS[0]; P[1] = sMS[1]; }
  if (t < 128) {
    float r = 0.f;
#pragma unroll
    for (int i = 0; i < 32; ++i) r += rPart[i][t] * scl[i];
    P[4 + t] = r;
  }
}

// ---------------------------------------------------------------------------
// k_s2s_combine: merge SPLIT partials -> r; q_star = [q|r]; then either the
// next step's LSTM (writes q,h,c) or, on the last step, the prediction.
// ---------------------------------------------------------------------------
__global__ __launch_bounds__(256) void k_s2s_combine(float* __restrict__ q_buf,
                                                     float* __restrict__ hc_buf,
                                                     const float* __restrict__ partials,
                                                     const float* __restrict__ w_ih,
                                                     const float* __restrict__ w_hh,
                                                     const float* __restrict__ b_ih,
                                                     const float* __restrict__ b_hh,
                                                     const float* __restrict__ Wp,
                                                     const float* __restrict__ bp,
                                                     float* __restrict__ out,
                                                     int last) {
  const int g = blockIdx.x, t = threadIdx.x;
  __shared__ float sc[SPLIT];
  __shared__ float qstar[256];
  __shared__ float hcl[256];
  __shared__ float gates[512];
  __shared__ float invS_sh;
  const float* P = partials + g * SPLIT * PSTR;

  if (t == 0) {
    float M = -INFINITY;
#pragma unroll
    for (int p = 0; p < SPLIT; ++p) M = fmaxf(M, P[p * PSTR]);
    float S = 0.f;
#pragma unroll
    for (int p = 0; p < SPLIT; ++p) {
      float mp = P[p * PSTR];
      float s_ = (mp > -INFINITY && M > -INFINITY) ? __expf(mp - M) : 0.f;
      sc[p] = s_;
      S += P[p * PSTR + 1] * s_;
    }
    invS_sh = (S > 0.f) ? __fdividef(1.f, S) : 0.f;
  }
  if (t < 128) {
    qstar[t] = q_buf[g * 128 + t];
    hcl[t] = hc_buf[g * 256 + t];
    hcl[128 + t] = hc_buf[g * 256 + 128 + t];
  }
  __syncthreads();
  if (t < 128) {
    float r = 0.f;
#pragma unroll
    for (int p = 0; p < SPLIT; ++p) r += P[p * PSTR + 4 + t] * sc[p];
    qstar[128 + t] = r * invS_sh;
  }
  __syncthreads();

  if (last) {
    // ---- prediction: out[g] = <q_star, W_pred> + b ----
    __shared__ float pr[256];
    pr[t] = qstar[t] * Wp[t];
    __syncthreads();
    if (t < 128) pr[t] += pr[t + 128];
    __syncthreads();
    if (t < 64) {
      float s = pr[t] + pr[t + 64];
#pragma unroll
      for (int o = 32; o > 0; o >>= 1) s += __shfl_xor(s, o, 64);
      if (t == 0) out[g] = s + bp[0];
    }
    return;
  }

  // ---- LSTM for the next step: gates = q_star@w_ih.T + h@w_hh.T + biases ----
#pragma unroll
  for (int rr = 0; rr < 2; ++rr) {
    int j = t + rr * 256;
    const float4* wi4 = (const float4*)(w_ih + j * 256);
    const float4* wh4 = (const float4*)(w_hh + j * 128);
    float s = 0.f;
#pragma unroll 8
    for (int k = 0; k < 64; ++k) {
      float4 a = wi4[k];
      float4 b = *(const float4*)&qstar[4 * k];
      s += a.x * b.x + a.y * b.y + a.z * b.z + a.w * b.w;
    }
#pragma unroll 8
    for (int k = 0; k < 32; ++k) {
      float4 a = wh4[k];
      float4 b = *(const float4*)&hcl[4 * k];
      s += a.x * b.x + a.y * b.y + a.z * b.z + a.w * b.w;
    }
    gates[j] = s + b_ih[j] + b_hh[j];
  }
  __syncthreads();
  if (t < 128) {
    float gi = gates[t], gf = gates[128 + t], gg = gates[256 + t], go = gates[384 + t];
    float c = sigmoid_f(gf) * hcl[128 + t] + sigmoid_f(gi) * tanh_f(gg);
    float hh = sigmoid_f(go) * tanh_f(c);
    hc_buf[g * 256 + t] = hh;
    hc_buf[g * 256 + 128 + t] = c;
    q_buf[g * 128 + t] = hh;
  }
}

// ---------------------------------------------------------------------------
extern "C" void kernel_launch(void* const* d_in, const int* in_sizes, int n_in,
                              void* d_out, int out_size, void* d_ws, size_t ws_size,
                              hipStream_t stream) {
  const float* x      = (const float*)d_in[0];
  const int*   ei     = (const int*)d_in[1];
  const int*   batch  = (const int*)d_in[2];
  const float* W_in   = (const float*)d_in[3];
  const float* b_in   = (const float*)d_in[4];
  const float* W_f    = (const float*)d_in[5];
  const float* U_f    = (const float*)d_in[6];
  const float* b_f    = (const float*)d_in[7];
  const float* W_h    = (const float*)d_in[8];
  const float* U_h    = (const float*)d_in[9];
  const float* b_h    = (const float*)d_in[10];
  const float* w_ih   = (const float*)d_in[11];
  const float* w_hh   = (const float*)d_in[12];
  const float* b_ih   = (const float*)d_in[13];
  const float* b_hh   = (const float*)d_in[14];
  const float* W_pred = (const float*)d_in[15];
  const float* b_pred = (const float*)d_in[16];
  float* out = (float*)d_out;

  char* ws = (char*)d_ws;
  float* h0     = (float*)(ws);                    // 51,200,000 B
  float* h1     = (float*)(ws + 51200000);         // 51,200,000 B (h ping-pong)
  int*   rowstart = (int*)(ws + 103063808);        //    400,016 B
  int*   srcSorted= (int*)(ws + 103463824);        //  2,560,000 B
  int*   bsum   = (int*)  (ws + 106023824);        //        112 B
  int*   boff   = (int*)  (ws + 106023936);        //        112 B
  // region at +102,400,000 (400,000 B): deg/cursor (CSR build) then Whi/Wlo
  int*    deg    = (int*)(ws + 102400000);
  int*    cursor = (int*)(ws + 102400000);
  __bf16* Whi    = (__bf16*)(ws + 102400000);      //    131,072 B
  __bf16* Wlo    = (__bf16*)(ws + 102531072);      //    131,072 B
  // Set2Set scratch lives in h0 (free after the last k_mgu reads it):
  float* q_buf    = (float*)(ws);                  //  65,536 B
  float* hc_buf   = (float*)(ws + 65536);          // 131,072 B
  float* partials = (float*)(ws + 196608);         // 128*4*132*4 = 270,336 B

  const int* src = ei;
  const int* dst = ei + N_EDGES;

  // ---- CSR build (once; reused by all 3 MPNN steps) ----
  hipMemsetAsync(deg, 0, N_NODES * 4, stream);
  k_hist<<<(N_EDGES + 255) / 256, 256, 0, stream>>>(dst, deg);
  k_scan_part<<<SCAN_NB, 256, 0, stream>>>(deg, bsum);
  k_scan_mid<<<1, 32, 0, stream>>>(bsum, boff, rowstart);
  k_scan_final<<<SCAN_NB, 256, 0, stream>>>(deg, boff, rowstart);
  hipMemcpyAsync(cursor, rowstart, N_NODES * 4, hipMemcpyDeviceToDevice, stream);
  k_fill<<<(N_EDGES + 255) / 256, 256, 0, stream>>>(src, dst, cursor, srcSorted);

  // ---- one-time weight bf16 hi/lo split (overwrites deg/cursor region) ----
  k_wsplit<<<256, 256, 0, stream>>>(W_f, U_f, W_h, U_h, Whi, Wlo);

  k_input<<<N_NODES / 32, 256, 0, stream>>>(x, W_in, b_in, h0);

  // ---- fused gather+MGU, h ping-pong: h0 -> h1 -> h0 -> h1 ----
  const int NBLK = N_NODES / 32;  // 3125, exact
  k_mgu<<<NBLK, 256, 0, stream>>>(h1, h0, rowstart, srcSorted, Whi, Wlo, b_f, b_h);
  k_mgu<<<NBLK, 256, 0, stream>>>(h0, h1, rowstart, srcSorted, Whi, Wlo, b_f, b_h);
  k_mgu<<<NBLK, 256, 0, stream>>>(h1, h0, rowstart, srcSorted, Whi, Wlo, b_f, b_h);

  // ---- Set2Set: init (step-0 LSTM), then 3x (scan + combine) ----
  k_s2s_init<<<NGRAPH, 128, 0, stream>>>(b_ih, b_hh, q_buf, hc_buf);
  for (int step = 0; step < 3; ++step) {
    k_s2s_scan<<<NGRAPH * SPLIT, 1024, 0, stream>>>(h1, batch, q_buf, partials);
    k_s2s_combine<<<NGRAPH, 256, 0, stream>>>(q_buf, hc_buf, partials,
                                              w_ih, w_hh, b_ih, b_hh,
                                              W_pred, b_pred, out, step == 2);
  }
}

// Round 7
// 797.231 us; speedup vs baseline: 2.1777x; 2.1777x over previous
//
#include <hip/hip_runtime.h>
#include <math.h>

#define N_NODES 100000
#define N_EDGES 640000
#define IN_DIM 64
#define HID 128
#define NGRAPH 128
#define SPLIT 4      // attention-scan blocks per graph
#define PSTR 132     // floats per partial record: [0]=M [1]=S [4..131]=R

typedef __bf16 bf16x2 __attribute__((ext_vector_type(2)));
typedef __bf16 bf16x4 __attribute__((ext_vector_type(4)));
typedef __bf16 bf16x8 __attribute__((ext_vector_type(8)));
typedef float f32x4 __attribute__((ext_vector_type(4)));

#define LDST 136  // bf16 elements per LDS row: 272 B, 16B-aligned, breaks pow2 stride

// fast transcendentals; inf-safe at both ends.
__device__ __forceinline__ float sigmoid_f(float z) {
  return __fdividef(1.f, 1.f + __expf(-z));
}
__device__ __forceinline__ float tanh_f(float z) {
  return 1.f - __fdividef(2.f, __expf(2.f * z) + 1.f);
}

// ---------------------------------------------------------------------------
// fma helper (used by k_input only)
// ---------------------------------------------------------------------------
__device__ __forceinline__ void fma44(const float4 A[4], const float4 B[4], float acc[4][4]) {
#pragma unroll
  for (int i2 = 0; i2 < 4; ++i2) {
    acc[i2][0] += A[i2].x*B[0].x + A[i2].y*B[1].x + A[i2].z*B[2].x + A[i2].w*B[3].x;
    acc[i2][1] += A[i2].x*B[0].y + A[i2].y*B[1].y + A[i2].z*B[2].y + A[i2].w*B[3].y;
    acc[i2][2] += A[i2].x*B[0].z + A[i2].y*B[1].z + A[i2].z*B[2].z + A[i2].w*B[3].z;
    acc[i2][3] += A[i2].x*B[0].w + A[i2].y*B[1].w + A[i2].z*B[2].w + A[i2].w*B[3].w;
  }
}

// ---------------------------------------------------------------------------
// Kernel 1: h = relu(x @ W_in.T + b_in)
// ---------------------------------------------------------------------------
__global__ __launch_bounds__(256) void k_input(const float* __restrict__ x,
                                               const float* __restrict__ W,
                                               const float* __restrict__ b,
                                               float* __restrict__ h) {
  __shared__ float wS[64][132];
  __shared__ float xS[32][68];
  int t = threadIdx.x;
  int nb = blockIdx.x * 32;
#pragma unroll
  for (int i = 0; i < 8; ++i) {
    int idx4 = i * 256 + t;
    int j = idx4 >> 4, kq = idx4 & 15;
    float4 v = ((const float4*)W)[j * 16 + kq];
    wS[4*kq+0][j] = v.x; wS[4*kq+1][j] = v.y; wS[4*kq+2][j] = v.z; wS[4*kq+3][j] = v.w;
  }
#pragma unroll
  for (int i = 0; i < 2; ++i) {
    int idx4 = i * 256 + t;
    int n = idx4 >> 4, kq = idx4 & 15;
    float4 v = ((const float4*)x)[(nb + n) * 16 + kq];
    *((float4*)&xS[n][4*kq]) = v;
  }
  __syncthreads();
  int bq = t & 31, a = t >> 5;
  float acc[4][4] = {};
#pragma unroll
  for (int kk4 = 0; kk4 < 16; ++kk4) {
    float4 A[4], B[4];
#pragma unroll
    for (int i2 = 0; i2 < 4; ++i2) A[i2] = *((const float4*)&xS[4*a+i2][4*kk4]);
#pragma unroll
    for (int c = 0; c < 4; ++c) B[c] = *((const float4*)&wS[4*kk4+c][4*bq]);
    fma44(A, B, acc);
  }
  float4 bb = ((const float4*)b)[bq];
  float ba[4] = {bb.x, bb.y, bb.z, bb.w};
#pragma unroll
  for (int i2 = 0; i2 < 4; ++i2) {
    float4 o;
    o.x = fmaxf(acc[i2][0] + ba[0], 0.f);
    o.y = fmaxf(acc[i2][1] + ba[1], 0.f);
    o.z = fmaxf(acc[i2][2] + ba[2], 0.f);
    o.w = fmaxf(acc[i2][3] + ba[3], 0.f);
    ((float4*)h)[(nb + 4*a + i2) * 32 + bq] = o;
  }
}

// ---------------------------------------------------------------------------
// CSR build: histogram -> scan -> fill
// ---------------------------------------------------------------------------
__global__ __launch_bounds__(256) void k_hist(const int* __restrict__ dst,
                                              int* __restrict__ deg) {
  int e = blockIdx.x * 256 + threadIdx.x;
  if (e < N_EDGES) atomicAdd(&deg[dst[e]], 1);
}

#define SCAN_CHUNK 4096
#define SCAN_NB 25

__global__ __launch_bounds__(256) void k_scan_part(const int* __restrict__ deg,
                                                   int* __restrict__ bsum) {
  __shared__ int red[256];
  int t = threadIdx.x, b = blockIdx.x;
  int base = b * SCAN_CHUNK + t * 16;
  int s = 0;
#pragma unroll
  for (int i = 0; i < 16; ++i) {
    int idx = base + i;
    if (idx < N_NODES) s += deg[idx];
  }
  red[t] = s;
  __syncthreads();
  for (int off = 128; off > 0; off >>= 1) {
    if (t < off) red[t] += red[t + off];
    __syncthreads();
  }
  if (t == 0) bsum[b] = red[0];
}

__global__ void k_scan_mid(const int* __restrict__ bsum, int* __restrict__ boff,
                           int* __restrict__ rowstart) {
  if (threadIdx.x == 0) {
    int run = 0;
    for (int i = 0; i < SCAN_NB; ++i) { boff[i] = run; run += bsum[i]; }
    rowstart[N_NODES] = run;
  }
}

__global__ __launch_bounds__(256) void k_scan_final(const int* __restrict__ deg,
                                                    const int* __restrict__ boff,
                                                    int* __restrict__ rowstart) {
  __shared__ int ts[256];
  int t = threadIdx.x, b = blockIdx.x;
  int base = b * SCAN_CHUNK + t * 16;
  int v[16];
  int s = 0;
#pragma unroll
  for (int i = 0; i < 16; ++i) {
    int idx = base + i;
    v[i] = (idx < N_NODES) ? deg[idx] : 0;
    s += v[i];
  }
  ts[t] = s;
  __syncthreads();
  for (int off = 1; off < 256; off <<= 1) {
    int add = (t >= off) ? ts[t - off] : 0;
    __syncthreads();
    ts[t] += add;
    __syncthreads();
  }
  int run = boff[b] + ts[t] - s;
#pragma unroll
  for (int i = 0; i < 16; ++i) {
    int idx = base + i;
    if (idx < N_NODES) rowstart[idx] = run;
    run += v[i];
  }
}

__global__ __launch_bounds__(256) void k_fill(const int* __restrict__ src,
                                              const int* __restrict__ dst,
                                              int* __restrict__ cursor,
                                              int* __restrict__ srcSorted) {
  int e = blockIdx.x * 256 + threadIdx.x;
  if (e >= N_EDGES) return;
  int d = dst[e];
  int p = atomicAdd(&cursor[d], 1);
  srcSorted[p] = src[e];
}

// ---------------------------------------------------------------------------
// One-time weight split fp32 -> bf16 (hi, lo). Layout preserved: [mat][j][k]
// ---------------------------------------------------------------------------
__global__ __launch_bounds__(256) void k_wsplit(const float* __restrict__ W0,
                                                const float* __restrict__ W1,
                                                const float* __restrict__ W2,
                                                const float* __restrict__ W3,
                                                __bf16* __restrict__ Whi,
                                                __bf16* __restrict__ Wlo) {
  int id = blockIdx.x * 256 + threadIdx.x;  // 65536 total
  int mat = id >> 14, idx = id & 16383;
  const float* W = (mat == 0) ? W0 : (mat == 1) ? W1 : (mat == 2) ? W2 : W3;
  float v = W[idx];
  __bf16 hi = (__bf16)v;
  Whi[id] = hi;
  Wlo[id] = (__bf16)(v - (float)hi);
}

// ---------------------------------------------------------------------------
// Aggregation (gather): m[n] = sum_{j in CSR[n]} h[srcSorted[j]]
// 32 lanes x float4 per node (one b128/lane/edge), 8 nodes/block, 2 in flight.
// (round-0 version — the measured-best MPNN composition; 3 fused variants all
// regressed, see session journal rounds 1-6.)
// ---------------------------------------------------------------------------
__global__ __launch_bounds__(256) void k_gather(const float* __restrict__ h,
                                                const int* __restrict__ rowstart,
                                                const int* __restrict__ srcSorted,
                                                float* __restrict__ m) {
  int node = blockIdx.x * 8 + (threadIdx.x >> 5);
  if (node >= N_NODES) return;
  int li = threadIdx.x & 31;
  int j0 = rowstart[node], j1 = rowstart[node + 1];
  const float4* h4 = (const float4*)h;
  float4 a0 = {0.f, 0.f, 0.f, 0.f}, a1 = {0.f, 0.f, 0.f, 0.f};
  int j = j0;
  for (; j + 1 < j1; j += 2) {
    int s0 = srcSorted[j], s1 = srcSorted[j + 1];
    float4 v0 = h4[s0 * 32 + li];
    float4 v1 = h4[s1 * 32 + li];
    a0.x += v0.x; a0.y += v0.y; a0.z += v0.z; a0.w += v0.w;
    a1.x += v1.x; a1.y += v1.y; a1.z += v1.z; a1.w += v1.w;
  }
  if (j < j1) {
    int s0 = srcSorted[j];
    float4 v0 = h4[s0 * 32 + li];
    a0.x += v0.x; a0.y += v0.y; a0.z += v0.z; a0.w += v0.w;
  }
  float4 o = {a0.x + a1.x, a0.y + a1.y, a0.z + a1.z, a0.w + a1.w};
  ((float4*)m)[node * 32 + li] = o;
}

// ---------------------------------------------------------------------------
// Fused MGU update, MFMA split-bf16, in-place on h (round-0 v5).
// 64 nodes/block, 256 threads, acc[4][2]/wave (8 independent MFMA chains).
// ---------------------------------------------------------------------------
__global__ __launch_bounds__(256) void k_mgu(float* __restrict__ h,
                                             const float* __restrict__ m,
                                             const __bf16* __restrict__ Whi,
                                             const __bf16* __restrict__ Wlo,
                                             const float* __restrict__ bfp,
                                             const float* __restrict__ bhp) {
  __shared__ __bf16 mHi[64 * LDST], mLo[64 * LDST];
  __shared__ __bf16 hHi[64 * LDST], hLo[64 * LDST];  // becomes g after f-gate
  const int t = threadIdx.x;
  const int nb = blockIdx.x * 64;

  // stage 64 rows x 128 of m and h, split to bf16 hi/lo
#pragma unroll
  for (int i = 0; i < 8; ++i) {
    int idx4 = i * 256 + t;
    int n = idx4 >> 5, kq = idx4 & 31;
    float4 vm = ((const float4*)m)[(nb + n) * 32 + kq];
    float4 vh = ((const float4*)h)[(nb + n) * 32 + kq];
    bf16x4 mh, ml, hh, hl;
    mh[0] = (__bf16)vm.x; ml[0] = (__bf16)(vm.x - (float)mh[0]);
    mh[1] = (__bf16)vm.y; ml[1] = (__bf16)(vm.y - (float)mh[1]);
    mh[2] = (__bf16)vm.z; ml[2] = (__bf16)(vm.z - (float)mh[2]);
    mh[3] = (__bf16)vm.w; ml[3] = (__bf16)(vm.w - (float)mh[3]);
    hh[0] = (__bf16)vh.x; hl[0] = (__bf16)(vh.x - (float)hh[0]);
    hh[1] = (__bf16)vh.y; hl[1] = (__bf16)(vh.y - (float)hh[1]);
    hh[2] = (__bf16)vh.z; hl[2] = (__bf16)(vh.z - (float)hh[2]);
    hh[3] = (__bf16)vh.w; hl[3] = (__bf16)(vh.w - (float)hh[3]);
    int e0 = n * LDST + 4 * kq;
    *(bf16x4*)&mHi[e0] = mh; *(bf16x4*)&mLo[e0] = ml;
    *(bf16x4*)&hHi[e0] = hh; *(bf16x4*)&hLo[e0] = hl;
  }
  __syncthreads();

  const int w = t >> 6, l = t & 63;
  const int lj = l & 15, q = l >> 4;

  float bfj[2], bhj[2];
#pragma unroll
  for (int ct = 0; ct < 2; ++ct) {
    int j = (2 * w + ct) * 16 + lj;
    bfj[ct] = bfp[j];
    bhj[ct] = bhp[j];
  }

  f32x4 acc[4][2] = {};

  // ---- phase A: z_f = m@Wf.T + h@Uf.T ----
#pragma unroll
  for (int kc = 0; kc < 128; kc += 32) {
    bf16x8 bwh[2], bwl[2], buh[2], bul[2];
#pragma unroll
    for (int ct = 0; ct < 2; ++ct) {
      int off = ((2 * w + ct) * 16 + lj) * 128 + kc + q * 8;
      bwh[ct] = *(const bf16x8*)&Whi[off];
      bwl[ct] = *(const bf16x8*)&Wlo[off];
      buh[ct] = *(const bf16x8*)&Whi[16384 + off];
      bul[ct] = *(const bf16x8*)&Wlo[16384 + off];
    }
#pragma unroll
    for (int rt = 0; rt < 4; ++rt) {
      int e0 = (rt * 16 + lj) * LDST + kc + q * 8;
      bf16x8 amh = *(const bf16x8*)&mHi[e0];
      bf16x8 aml = *(const bf16x8*)&mLo[e0];
      bf16x8 ahh = *(const bf16x8*)&hHi[e0];
      bf16x8 ahl = *(const bf16x8*)&hLo[e0];
#pragma unroll
      for (int ct = 0; ct < 2; ++ct) {
        f32x4 a = acc[rt][ct];
        a = __builtin_amdgcn_mfma_f32_16x16x32_bf16(amh, bwh[ct], a, 0, 0, 0);
        a = __builtin_amdgcn_mfma_f32_16x16x32_bf16(amh, bwl[ct], a, 0, 0, 0);
        a = __builtin_amdgcn_mfma_f32_16x16x32_bf16(aml, bwh[ct], a, 0, 0, 0);
        a = __builtin_amdgcn_mfma_f32_16x16x32_bf16(ahh, buh[ct], a, 0, 0, 0);
        a = __builtin_amdgcn_mfma_f32_16x16x32_bf16(ahh, bul[ct], a, 0, 0, 0);
        a = __builtin_amdgcn_mfma_f32_16x16x32_bf16(ahl, buh[ct], a, 0, 0, 0);
        acc[rt][ct] = a;
      }
    }
  }

  // ---- transition: f = sigmoid(z_f + bf); g = f*h overwrites h tile ----
  __syncthreads();  // all phase-A reads of hHi/hLo complete
  float fv[4][2][4], hvv[4][2][4];
#pragma unroll
  for (int rt = 0; rt < 4; ++rt)
#pragma unroll
    for (int ct = 0; ct < 2; ++ct) {
      int j = (2 * w + ct) * 16 + lj;
#pragma unroll
      for (int r = 0; r < 4; ++r) {
        int nl = rt * 16 + q * 4 + r;
        float z = acc[rt][ct][r] + bfj[ct];
        float f = sigmoid_f(z);
        int he = nl * LDST + j;
        float hval = (float)hHi[he] + (float)hLo[he];
        float g = f * hval;
        __bf16 ghi = (__bf16)g;
        hHi[he] = ghi;
        hLo[he] = (__bf16)(g - (float)ghi);
        fv[rt][ct][r] = f;
        hvv[rt][ct][r] = hval;
        acc[rt][ct][r] = 0.f;
      }
    }
  __syncthreads();

  // ---- phase B: z_h = m@Wh.T + g@Uh.T ----
#pragma unroll
  for (int kc = 0; kc < 128; kc += 32) {
    bf16x8 bwh[2], bwl[2], buh[2], bul[2];
#pragma unroll
    for (int ct = 0; ct < 2; ++ct) {
      int off = ((2 * w + ct) * 16 + lj) * 128 + kc + q * 8;
      bwh[ct] = *(const bf16x8*)&Whi[2 * 16384 + off];
      bwl[ct] = *(const bf16x8*)&Wlo[2 * 16384 + off];
      buh[ct] = *(const bf16x8*)&Whi[3 * 16384 + off];
      bul[ct] = *(const bf16x8*)&Wlo[3 * 16384 + off];
    }
#pragma unroll
    for (int rt = 0; rt < 4; ++rt) {
      int e0 = (rt * 16 + lj) * LDST + kc + q * 8;
      bf16x8 amh = *(const bf16x8*)&mHi[e0];
      bf16x8 aml = *(const bf16x8*)&mLo[e0];
      bf16x8 agh = *(const bf16x8*)&hHi[e0];
      bf16x8 agl = *(const bf16x8*)&hLo[e0];
#pragma unroll
      for (int ct = 0; ct < 2; ++ct) {
        f32x4 a = acc[rt][ct];
        a = __builtin_amdgcn_mfma_f32_16x16x32_bf16(amh, bwh[ct], a, 0, 0, 0);
        a = __builtin_amdgcn_mfma_f32_16x16x32_bf16(amh, bwl[ct], a, 0, 0, 0);
        a = __builtin_amdgcn_mfma_f32_16x16x32_bf16(aml, bwh[ct], a, 0, 0, 0);
        a = __builtin_amdgcn_mfma_f32_16x16x32_bf16(agh, buh[ct], a, 0, 0, 0);
        a = __builtin_amdgcn_mfma_f32_16x16x32_bf16(agh, bul[ct], a, 0, 0, 0);
        a = __builtin_amdgcn_mfma_f32_16x16x32_bf16(agl, buh[ct], a, 0, 0, 0);
        acc[rt][ct] = a;
      }
    }
  }

  // ---- epilogue: h = (1-f)*h + f*tanh(z_h + bh) ----
#pragma unroll
  for (int rt = 0; rt < 4; ++rt)
#pragma unroll
    for (int ct = 0; ct < 2; ++ct) {
      int j = (2 * w + ct) * 16 + lj;
#pragma unroll
      for (int r = 0; r < 4; ++r) {
        float T = tanh_f(acc[rt][ct][r] + bhj[ct]);
        float f = fv[rt][ct][r];
        float hn = (1.f - f) * hvv[rt][ct][r] + f * T;
        h[(nb + rt * 16 + q * 4 + r) * 128 + j] = hn;
      }
    }
}

// ---------------------------------------------------------------------------
// Set2Set v2: init + 3x step. Each step: 512 blocks (4 per graph) scan with
// online softmax; the LAST finisher of each graph's 4 blocks (device-scope
// atomic counter, no spinning) merges the partials and runs the LSTM (or the
// final prediction). Combine overlaps other graphs' scans; no combine launch.
// ---------------------------------------------------------------------------
__global__ __launch_bounds__(128) void k_s2s_init(const float* __restrict__ b_ih,
                                                  const float* __restrict__ b_hh,
                                                  float* __restrict__ q_buf,
                                                  float* __restrict__ hc_buf,
                                                  int* __restrict__ done) {
  int g = blockIdx.x, t = threadIdx.x;
  float gi = b_ih[t] + b_hh[t];
  float gf = b_ih[128 + t] + b_hh[128 + t];
  float gg = b_ih[256 + t] + b_hh[256 + t];
  float go = b_ih[384 + t] + b_hh[384 + t];
  (void)gf;  // c_prev = 0 -> forget path contributes nothing at step 0
  float c = sigmoid_f(gi) * tanh_f(gg);
  float hh = sigmoid_f(go) * tanh_f(c);
  q_buf[g * 128 + t] = hh;
  hc_buf[g * 256 + t] = hh;
  hc_buf[g * 256 + 128 + t] = c;
  if (t < 3) done[t * NGRAPH + g] = 0;   // reset flags for this launch
}

__global__ __launch_bounds__(1024, 8) void k_s2s_step(const float* __restrict__ h,
                                                      const int* __restrict__ batch,
                                                      float* __restrict__ q_buf,
                                                      float* __restrict__ hc_buf,
                                                      float* __restrict__ partials,
                                                      int* __restrict__ done,
                                                      const float* __restrict__ w_ih,
                                                      const float* __restrict__ w_hh,
                                                      const float* __restrict__ b_ih,
                                                      const float* __restrict__ b_hh,
                                                      const float* __restrict__ Wp,
                                                      const float* __restrict__ bp,
                                                      float* __restrict__ out,
                                                      int step) {
  const int b = blockIdx.x;
  const int g = b >> 2, p = b & (SPLIT - 1);
  const int t = threadIdx.x;
  const int w = t >> 6, l = t & 63;
  const int half = l >> 5, li = l & 31;
  const int hw = 2 * w + half;           // stream id 0..31
  __shared__ float redM[32], redS[32], scl[32];
  __shared__ float rPart[32][132];
  __shared__ float sMS[2];
  __shared__ int bnd[2];
  __shared__ int amLast;

  if (t < 2) {
    int tgt = g + t;
    int lo = 0, hi = N_NODES;
    while (lo < hi) { int mid = (lo + hi) >> 1; if (batch[mid] < tgt) lo = mid + 1; else hi = mid; }
    bnd[t] = lo;
  }
  __syncthreads();
  const int s0 = bnd[0], s1 = bnd[1];
  const int len = s1 - s0;
  const int ps = s0 + (len * p) / SPLIT;
  const int pe = s0 + (len * (p + 1)) / SPLIT;

  // per-lane query slice
  float4 qv = ((const float4*)(q_buf + g * 128))[li];
  const float q0 = qv.x, q1 = qv.y, q2 = qv.z, q3 = qv.w;

  float mw = -INFINITY, sw = 0.f;
  float4 racc = {0.f, 0.f, 0.f, 0.f};
  const float4* h4 = (const float4*)h;
  int n = ps + hw;
  for (; n + 32 < pe; n += 64) {
    float4 hv0 = h4[n * 32 + li];
    float4 hv1 = h4[(n + 32) * 32 + li];
    float v0 = hv0.x * q0 + hv0.y * q1 + hv0.z * q2 + hv0.w * q3;
    float v1 = hv1.x * q0 + hv1.y * q1 + hv1.z * q2 + hv1.w * q3;
#pragma unroll
    for (int o = 16; o > 0; o >>= 1) {
      v0 += __shfl_xor(v0, o, 64);
      v1 += __shfl_xor(v1, o, 64);
    }
    float nm = fmaxf(mw, fmaxf(v0, v1));
    float sc = __expf(mw - nm);
    float w0 = __expf(v0 - nm);
    float w1 = __expf(v1 - nm);
    sw = sw * sc + w0 + w1;
    racc.x = racc.x * sc + w0 * hv0.x + w1 * hv1.x;
    racc.y = racc.y * sc + w0 * hv0.y + w1 * hv1.y;
    racc.z = racc.z * sc + w0 * hv0.z + w1 * hv1.z;
    racc.w = racc.w * sc + w0 * hv0.w + w1 * hv1.w;
    mw = nm;
  }
  for (; n < pe; n += 32) {
    float4 hv = h4[n * 32 + li];
    float v = hv.x * q0 + hv.y * q1 + hv.z * q2 + hv.w * q3;
#pragma unroll
    for (int o = 16; o > 0; o >>= 1) v += __shfl_xor(v, o, 64);
    float nm = fmaxf(mw, v);
    float sc = __expf(mw - nm);
    float wg = __expf(v - nm);
    sw = sw * sc + wg;
    racc.x = racc.x * sc + wg * hv.x;
    racc.y = racc.y * sc + wg * hv.y;
    racc.z = racc.z * sc + wg * hv.z;
    racc.w = racc.w * sc + wg * hv.w;
    mw = nm;
  }
  if (li == 0) { redM[hw] = mw; redS[hw] = sw; }
  *(float4*)&rPart[hw][4 * li] = racc;
  __syncthreads();
  if (t == 0) {
    float M = -INFINITY;
    for (int i = 0; i < 32; ++i) M = fmaxf(M, redM[i]);
    float S = 0.f;
    for (int i = 0; i < 32; ++i) {
      float s_ = (redM[i] > -INFINITY && M > -INFINITY) ? __expf(redM[i] - M) : 0.f;
      scl[i] = s_;
      S += redS[i] * s_;
    }
    sMS[0] = M; sMS[1] = S;
  }
  __syncthreads();
  float* P = partials + (g * SPLIT + p) * PSTR;
  if (t == 0) { P[0] = sMS[0]; P[1] = sMS[1]; }
  if (t < 128) {
    float r = 0.f;
#pragma unroll
    for (int i = 0; i < 32; ++i) r += rPart[i][t] * scl[i];
    P[4 + t] = r;
  }

  // ---- arrive: last finisher of this graph's 4 blocks does the combine ----
  __syncthreads();                 // all partial stores issued & drained (vmcnt0)
  if (t == 0) {
    __threadfence();               // write-back local L2 -> device visible
    int old = atomicAdd(&done[step * NGRAPH + g], 1);
    amLast = (old == 3);
  }
  __syncthreads();
  if (!amLast) return;
  if (t == 0) __threadfence();     // invalidate stale L1/L2 before reading partials
  __syncthreads();

  // ---- combine: merge 4 partials -> r; q_star = [q|r] ----
  __shared__ float sc2[SPLIT];
  __shared__ float qstar[256];
  __shared__ float hcl[256];
  __shared__ float gates[512];
  __shared__ float invS_sh;
  const float* PP = partials + g * SPLIT * PSTR;

  if (t == 0) {
    float M = -INFINITY;
#pragma unroll
    for (int pp = 0; pp < SPLIT; ++pp) M = fmaxf(M, PP[pp * PSTR]);
    float S = 0.f;
#pragma unroll
    for (int pp = 0; pp < SPLIT; ++pp) {
      float mp = PP[pp * PSTR];
      float s_ = (mp > -INFINITY && M > -INFINITY) ? __expf(mp - M) : 0.f;
      sc2[pp] = s_;
      S += PP[pp * PSTR + 1] * s_;
    }
    invS_sh = (S > 0.f) ? __fdividef(1.f, S) : 0.f;
  }
  if (t < 128) {
    qstar[t] = q_buf[g * 128 + t];
    hcl[t] = hc_buf[g * 256 + t];
    hcl[128 + t] = hc_buf[g * 256 + 128 + t];
  }
  __syncthreads();
  if (t < 128) {
    float r = 0.f;
#pragma unroll
    for (int pp = 0; pp < SPLIT; ++pp) r += PP[pp * PSTR + 4 + t] * sc2[pp];
    qstar[128 + t] = r * invS_sh;
  }
  __syncthreads();

  if (step == 2) {
    // ---- prediction: out[g] = <q_star, W_pred> + b ----
    __shared__ float pr[256];
    if (t < 256) pr[t] = qstar[t] * Wp[t];
    __syncthreads();
    if (t < 128) pr[t] += pr[t + 128];
    __syncthreads();
    if (t < 64) {
      float s = pr[t] + pr[t + 64];
#pragma unroll
      for (int o = 32; o > 0; o >>= 1) s += __shfl_xor(s, o, 64);
      if (t == 0) out[g] = s + bp[0];
    }
    return;
  }

  // ---- LSTM for the next step: gates = q_star@w_ih.T + h@w_hh.T + biases ----
  if (t < 512) {
    int j = t;
    const float4* wi4 = (const float4*)(w_ih + j * 256);
    const float4* wh4 = (const float4*)(w_hh + j * 128);
    float s = 0.f;
#pragma unroll 8
    for (int k = 0; k < 64; ++k) {
      float4 a = wi4[k];
      float4 bb = *(const float4*)&qstar[4 * k];
      s += a.x * bb.x + a.y * bb.y + a.z * bb.z + a.w * bb.w;
    }
#pragma unroll 8
    for (int k = 0; k < 32; ++k) {
      float4 a = wh4[k];
      float4 bb = *(const float4*)&hcl[4 * k];
      s += a.x * bb.x + a.y * bb.y + a.z * bb.z + a.w * bb.w;
    }
    gates[j] = s + b_ih[j] + b_hh[j];
  }
  __syncthreads();
  if (t < 128) {
    float gi = gates[t], gf = gates[128 + t], gg = gates[256 + t], go = gates[384 + t];
    float c = sigmoid_f(gf) * hcl[128 + t] + sigmoid_f(gi) * tanh_f(gg);
    float hh = sigmoid_f(go) * tanh_f(c);
    hc_buf[g * 256 + t] = hh;
    hc_buf[g * 256 + 128 + t] = c;
    q_buf[g * 128 + t] = hh;
  }
  // launch boundary of the next step provides the release/acquire for q_buf.
}

// ---------------------------------------------------------------------------
extern "C" void kernel_launch(void* const* d_in, const int* in_sizes, int n_in,
                              void* d_out, int out_size, void* d_ws, size_t ws_size,
                              hipStream_t stream) {
  const float* x      = (const float*)d_in[0];
  const int*   ei     = (const int*)d_in[1];
  const int*   batch  = (const int*)d_in[2];
  const float* W_in   = (const float*)d_in[3];
  const float* b_in   = (const float*)d_in[4];
  const float* W_f    = (const float*)d_in[5];
  const float* U_f    = (const float*)d_in[6];
  const float* b_f    = (const float*)d_in[7];
  const float* W_h    = (const float*)d_in[8];
  const float* U_h    = (const float*)d_in[9];
  const float* b_h    = (const float*)d_in[10];
  const float* w_ih   = (const float*)d_in[11];
  const float* w_hh   = (const float*)d_in[12];
  const float* b_ih   = (const float*)d_in[13];
  const float* b_hh   = (const float*)d_in[14];
  const float* W_pred = (const float*)d_in[15];
  const float* b_pred = (const float*)d_in[16];
  float* out = (float*)d_out;

  char* ws = (char*)d_ws;
  float* h      = (float*)(ws);                    // 51,200,000 B
  float* m      = (float*)(ws + 51200000);         // 51,200,000 B
  int*   rowstart = (int*)(ws + 103063808);        //    400,016 B
  int*   srcSorted= (int*)(ws + 103463824);        //  2,560,000 B
  int*   bsum   = (int*)  (ws + 106023824);        //        112 B
  int*   boff   = (int*)  (ws + 106023936);        //        112 B
  // region at +102,400,000 (400,000 B): deg/cursor (CSR build) then Whi/Wlo
  int*    deg    = (int*)(ws + 102400000);
  int*    cursor = (int*)(ws + 102400000);
  __bf16* Whi    = (__bf16*)(ws + 102400000);      //    131,072 B
  __bf16* Wlo    = (__bf16*)(ws + 102531072);      //    131,072 B
  // Set2Set scratch lives in the m region (free after the last k_mgu):
  float* q_buf    = (float*)(ws + 51200000);           //  65,536 B
  float* hc_buf   = (float*)(ws + 51200000 + 65536);   // 131,072 B
  float* partials = (float*)(ws + 51200000 + 196608);  // 270,336 B
  int*   done     = (int*)  (ws + 51200000 + 466944);  //   1,536 B

  const int* src = ei;
  const int* dst = ei + N_EDGES;

  // ---- CSR build (once; reused by all 3 MPNN steps) ----
  hipMemsetAsync(deg, 0, N_NODES * 4, stream);
  k_hist<<<(N_EDGES + 255) / 256, 256, 0, stream>>>(dst, deg);
  k_scan_part<<<SCAN_NB, 256, 0, stream>>>(deg, bsum);
  k_scan_mid<<<1, 32, 0, stream>>>(bsum, boff, rowstart);
  k_scan_final<<<SCAN_NB, 256, 0, stream>>>(deg, boff, rowstart);
  hipMemcpyAsync(cursor, rowstart, N_NODES * 4, hipMemcpyDeviceToDevice, stream);
  k_fill<<<(N_EDGES + 255) / 256, 256, 0, stream>>>(src, dst, cursor, srcSorted);

  // ---- one-time weight bf16 hi/lo split (overwrites deg/cursor region) ----
  k_wsplit<<<256, 256, 0, stream>>>(W_f, U_f, W_h, U_h, Whi, Wlo);

  k_input<<<N_NODES / 32, 256, 0, stream>>>(x, W_in, b_in, h);

  // ---- MPNN: gather + in-place MGU (round-0 measured-best composition) ----
  for (int step = 0; step < 3; ++step) {
    k_gather<<<(N_NODES + 7) / 8, 256, 0, stream>>>(h, rowstart, srcSorted, m);
    k_mgu<<<(N_NODES + 63) / 64, 256, 0, stream>>>(h, m, Whi, Wlo, b_f, b_h);
  }

  // ---- Set2Set: init, then 3x (512-block scan + last-finisher combine) ----
  k_s2s_init<<<NGRAPH, 128, 0, stream>>>(b_ih, b_hh, q_buf, hc_buf, done);
  for (int step = 0; step < 3; ++step) {
    k_s2s_step<<<NGRAPH * SPLIT, 1024, 0, stream>>>(h, batch, q_buf, hc_buf,
                                                    partials, done,
                                                    w_ih, w_hh, b_ih, b_hh,
                                                    W_pred, b_pred, out, step);
  }
}

// Round 8
// 776.584 us; speedup vs baseline: 2.2356x; 1.0266x over previous
//
#include <hip/hip_runtime.h>
#include <math.h>

#define N_NODES 100000
#define N_EDGES 640000
#define IN_DIM 64
#define HID 128
#define NGRAPH 128

typedef __bf16 bf16x2 __attribute__((ext_vector_type(2)));
typedef __bf16 bf16x4 __attribute__((ext_vector_type(4)));
typedef __bf16 bf16x8 __attribute__((ext_vector_type(8)));
typedef float f32x4 __attribute__((ext_vector_type(4)));

#define LDST 136  // bf16 elements per LDS row: 272 B, 16B-aligned, breaks pow2 stride

// fast transcendentals; inf-safe at both ends.
__device__ __forceinline__ float sigmoid_f(float z) {
  return __fdividef(1.f, 1.f + __expf(-z));
}
__device__ __forceinline__ float tanh_f(float z) {
  return 1.f - __fdividef(2.f, __expf(2.f * z) + 1.f);
}

// ---------------------------------------------------------------------------
// fma helper (used by k_input only)
// ---------------------------------------------------------------------------
__device__ __forceinline__ void fma44(const float4 A[4], const float4 B[4], float acc[4][4]) {
#pragma unroll
  for (int i2 = 0; i2 < 4; ++i2) {
    acc[i2][0] += A[i2].x*B[0].x + A[i2].y*B[1].x + A[i2].z*B[2].x + A[i2].w*B[3].x;
    acc[i2][1] += A[i2].x*B[0].y + A[i2].y*B[1].y + A[i2].z*B[2].y + A[i2].w*B[3].y;
    acc[i2][2] += A[i2].x*B[0].z + A[i2].y*B[1].z + A[i2].z*B[2].z + A[i2].w*B[3].z;
    acc[i2][3] += A[i2].x*B[0].w + A[i2].y*B[1].w + A[i2].z*B[2].w + A[i2].w*B[3].w;
  }
}

// ---------------------------------------------------------------------------
// Kernel 1: h = relu(x @ W_in.T + b_in)
// ---------------------------------------------------------------------------
__global__ __launch_bounds__(256) void k_input(const float* __restrict__ x,
                                               const float* __restrict__ W,
                                               const float* __restrict__ b,
                                               float* __restrict__ h) {
  __shared__ float wS[64][132];
  __shared__ float xS[32][68];
  int t = threadIdx.x;
  int nb = blockIdx.x * 32;
#pragma unroll
  for (int i = 0; i < 8; ++i) {
    int idx4 = i * 256 + t;
    int j = idx4 >> 4, kq = idx4 & 15;
    float4 v = ((const float4*)W)[j * 16 + kq];
    wS[4*kq+0][j] = v.x; wS[4*kq+1][j] = v.y; wS[4*kq+2][j] = v.z; wS[4*kq+3][j] = v.w;
  }
#pragma unroll
  for (int i = 0; i < 2; ++i) {
    int idx4 = i * 256 + t;
    int n = idx4 >> 4, kq = idx4 & 15;
    float4 v = ((const float4*)x)[(nb + n) * 16 + kq];
    *((float4*)&xS[n][4*kq]) = v;
  }
  __syncthreads();
  int bq = t & 31, a = t >> 5;
  float acc[4][4] = {};
#pragma unroll
  for (int kk4 = 0; kk4 < 16; ++kk4) {
    float4 A[4], B[4];
#pragma unroll
    for (int i2 = 0; i2 < 4; ++i2) A[i2] = *((const float4*)&xS[4*a+i2][4*kk4]);
#pragma unroll
    for (int c = 0; c < 4; ++c) B[c] = *((const float4*)&wS[4*kk4+c][4*bq]);
    fma44(A, B, acc);
  }
  float4 bb = ((const float4*)b)[bq];
  float ba[4] = {bb.x, bb.y, bb.z, bb.w};
#pragma unroll
  for (int i2 = 0; i2 < 4; ++i2) {
    float4 o;
    o.x = fmaxf(acc[i2][0] + ba[0], 0.f);
    o.y = fmaxf(acc[i2][1] + ba[1], 0.f);
    o.z = fmaxf(acc[i2][2] + ba[2], 0.f);
    o.w = fmaxf(acc[i2][3] + ba[3], 0.f);
    ((float4*)h)[(nb + 4*a + i2) * 32 + bq] = o;
  }
}

// ---------------------------------------------------------------------------
// CSR build: histogram -> scan -> fill
// ---------------------------------------------------------------------------
__global__ __launch_bounds__(256) void k_hist(const int* __restrict__ dst,
                                              int* __restrict__ deg) {
  int e = blockIdx.x * 256 + threadIdx.x;
  if (e < N_EDGES) atomicAdd(&deg[dst[e]], 1);
}

#define SCAN_CHUNK 4096
#define SCAN_NB 25

__global__ __launch_bounds__(256) void k_scan_part(const int* __restrict__ deg,
                                                   int* __restrict__ bsum) {
  __shared__ int red[256];
  int t = threadIdx.x, b = blockIdx.x;
  int base = b * SCAN_CHUNK + t * 16;
  int s = 0;
#pragma unroll
  for (int i = 0; i < 16; ++i) {
    int idx = base + i;
    if (idx < N_NODES) s += deg[idx];
  }
  red[t] = s;
  __syncthreads();
  for (int off = 128; off > 0; off >>= 1) {
    if (t < off) red[t] += red[t + off];
    __syncthreads();
  }
  if (t == 0) bsum[b] = red[0];
}

__global__ void k_scan_mid(const int* __restrict__ bsum, int* __restrict__ boff,
                           int* __restrict__ rowstart) {
  if (threadIdx.x == 0) {
    int run = 0;
    for (int i = 0; i < SCAN_NB; ++i) { boff[i] = run; run += bsum[i]; }
    rowstart[N_NODES] = run;
  }
}

__global__ __launch_bounds__(256) void k_scan_final(const int* __restrict__ deg,
                                                    const int* __restrict__ boff,
                                                    int* __restrict__ rowstart) {
  __shared__ int ts[256];
  int t = threadIdx.x, b = blockIdx.x;
  int base = b * SCAN_CHUNK + t * 16;
  int v[16];
  int s = 0;
#pragma unroll
  for (int i = 0; i < 16; ++i) {
    int idx = base + i;
    v[i] = (idx < N_NODES) ? deg[idx] : 0;
    s += v[i];
  }
  ts[t] = s;
  __syncthreads();
  for (int off = 1; off < 256; off <<= 1) {
    int add = (t >= off) ? ts[t - off] : 0;
    __syncthreads();
    ts[t] += add;
    __syncthreads();
  }
  int run = boff[b] + ts[t] - s;
#pragma unroll
  for (int i = 0; i < 16; ++i) {
    int idx = base + i;
    if (idx < N_NODES) rowstart[idx] = run;
    run += v[i];
  }
}

__global__ __launch_bounds__(256) void k_fill(const int* __restrict__ src,
                                              const int* __restrict__ dst,
                                              int* __restrict__ cursor,
                                              int* __restrict__ srcSorted) {
  int e = blockIdx.x * 256 + threadIdx.x;
  if (e >= N_EDGES) return;
  int d = dst[e];
  int p = atomicAdd(&cursor[d], 1);
  srcSorted[p] = src[e];
}

// ---------------------------------------------------------------------------
// One-time weight split fp32 -> bf16 (hi, lo). Layout preserved: [mat][j][k]
// ---------------------------------------------------------------------------
__global__ __launch_bounds__(256) void k_wsplit(const float* __restrict__ W0,
                                                const float* __restrict__ W1,
                                                const float* __restrict__ W2,
                                                const float* __restrict__ W3,
                                                __bf16* __restrict__ Whi,
                                                __bf16* __restrict__ Wlo) {
  int id = blockIdx.x * 256 + threadIdx.x;  // 65536 total
  int mat = id >> 14, idx = id & 16383;
  const float* W = (mat == 0) ? W0 : (mat == 1) ? W1 : (mat == 2) ? W2 : W3;
  float v = W[idx];
  __bf16 hi = (__bf16)v;
  Whi[id] = hi;
  Wlo[id] = (__bf16)(v - (float)hi);
}

// ---------------------------------------------------------------------------
// Aggregation (gather): m[n] = sum_{j in CSR[n]} h[srcSorted[j]]
// 32 lanes x float4 per node, 8 nodes/block, 2 edges in flight. (round-0,
// measured-best; 3 fused/restructured variants all regressed, rounds 1-6.)
// ---------------------------------------------------------------------------
__global__ __launch_bounds__(256) void k_gather(const float* __restrict__ h,
                                                const int* __restrict__ rowstart,
                                                const int* __restrict__ srcSorted,
                                                float* __restrict__ m) {
  int node = blockIdx.x * 8 + (threadIdx.x >> 5);
  if (node >= N_NODES) return;
  int li = threadIdx.x & 31;
  int j0 = rowstart[node], j1 = rowstart[node + 1];
  const float4* h4 = (const float4*)h;
  float4 a0 = {0.f, 0.f, 0.f, 0.f}, a1 = {0.f, 0.f, 0.f, 0.f};
  int j = j0;
  for (; j + 1 < j1; j += 2) {
    int s0 = srcSorted[j], s1 = srcSorted[j + 1];
    float4 v0 = h4[s0 * 32 + li];
    float4 v1 = h4[s1 * 32 + li];
    a0.x += v0.x; a0.y += v0.y; a0.z += v0.z; a0.w += v0.w;
    a1.x += v1.x; a1.y += v1.y; a1.z += v1.z; a1.w += v1.w;
  }
  if (j < j1) {
    int s0 = srcSorted[j];
    float4 v0 = h4[s0 * 32 + li];
    a0.x += v0.x; a0.y += v0.y; a0.z += v0.z; a0.w += v0.w;
  }
  float4 o = {a0.x + a1.x, a0.y + a1.y, a0.z + a1.z, a0.w + a1.w};
  ((float4*)m)[node * 32 + li] = o;
}

// ---------------------------------------------------------------------------
// Fused MGU update, MFMA split-bf16, in-place on h.
// v11: standalone mgu at 32 nodes/block. LDS 34,816 B -> 4 blocks/CU
// (vs 2 at 64 nodes): doubles the co-resident latency hiding for the
// staging/epilogue phases (mgu-64 measured 120 us at 19.5% occupancy,
// nothing saturated). MFMA body identical to the round-2-verified v7.
// ---------------------------------------------------------------------------
__global__ __launch_bounds__(256, 4) void k_mgu(float* __restrict__ h,
                                                const float* __restrict__ m,
                                                const __bf16* __restrict__ Whi,
                                                const __bf16* __restrict__ Wlo,
                                                const float* __restrict__ bfp,
                                                const float* __restrict__ bhp) {
  __shared__ __bf16 mHi[32 * LDST], mLo[32 * LDST];
  __shared__ __bf16 hHi[32 * LDST], hLo[32 * LDST];  // becomes g after f-gate
  const int t = threadIdx.x;
  const int nb = blockIdx.x * 32;

  // stage 32 rows x 128 of m and h, split to bf16 hi/lo
#pragma unroll
  for (int i = 0; i < 4; ++i) {
    int idx4 = i * 256 + t;
    int n = idx4 >> 5, kq = idx4 & 31;
    float4 vm = ((const float4*)m)[(nb + n) * 32 + kq];
    float4 vh = ((const float4*)h)[(nb + n) * 32 + kq];
    bf16x4 mh, ml, hh, hl;
    mh[0] = (__bf16)vm.x; ml[0] = (__bf16)(vm.x - (float)mh[0]);
    mh[1] = (__bf16)vm.y; ml[1] = (__bf16)(vm.y - (float)mh[1]);
    mh[2] = (__bf16)vm.z; ml[2] = (__bf16)(vm.z - (float)mh[2]);
    mh[3] = (__bf16)vm.w; ml[3] = (__bf16)(vm.w - (float)mh[3]);
    hh[0] = (__bf16)vh.x; hl[0] = (__bf16)(vh.x - (float)hh[0]);
    hh[1] = (__bf16)vh.y; hl[1] = (__bf16)(vh.y - (float)hh[1]);
    hh[2] = (__bf16)vh.z; hl[2] = (__bf16)(vh.z - (float)hh[2]);
    hh[3] = (__bf16)vh.w; hl[3] = (__bf16)(vh.w - (float)hh[3]);
    int e0 = n * LDST + 4 * kq;
    *(bf16x4*)&mHi[e0] = mh; *(bf16x4*)&mLo[e0] = ml;
    *(bf16x4*)&hHi[e0] = hh; *(bf16x4*)&hLo[e0] = hl;
  }
  __syncthreads();

  const int w = t >> 6, l = t & 63;
  const int lj = l & 15, q = l >> 4;

  float bfj[2], bhj[2];
#pragma unroll
  for (int ct = 0; ct < 2; ++ct) {
    int j = (2 * w + ct) * 16 + lj;
    bfj[ct] = bfp[j];
    bhj[ct] = bhp[j];
  }

  f32x4 acc[2][2] = {};

  // ---- phase A: z_f = m@Wf.T + h@Uf.T ----
#pragma unroll
  for (int kc = 0; kc < 128; kc += 32) {
    bf16x8 bwh[2], bwl[2], buh[2], bul[2];
#pragma unroll
    for (int ct = 0; ct < 2; ++ct) {
      int off = ((2 * w + ct) * 16 + lj) * 128 + kc + q * 8;
      bwh[ct] = *(const bf16x8*)&Whi[off];
      bwl[ct] = *(const bf16x8*)&Wlo[off];
      buh[ct] = *(const bf16x8*)&Whi[16384 + off];
      bul[ct] = *(const bf16x8*)&Wlo[16384 + off];
    }
#pragma unroll
    for (int rt = 0; rt < 2; ++rt) {
      int e0 = (rt * 16 + lj) * LDST + kc + q * 8;
      bf16x8 amh = *(const bf16x8*)&mHi[e0];
      bf16x8 aml = *(const bf16x8*)&mLo[e0];
      bf16x8 ahh = *(const bf16x8*)&hHi[e0];
      bf16x8 ahl = *(const bf16x8*)&hLo[e0];
#pragma unroll
      for (int ct = 0; ct < 2; ++ct) {
        f32x4 a = acc[rt][ct];
        a = __builtin_amdgcn_mfma_f32_16x16x32_bf16(amh, bwh[ct], a, 0, 0, 0);
        a = __builtin_amdgcn_mfma_f32_16x16x32_bf16(amh, bwl[ct], a, 0, 0, 0);
        a = __builtin_amdgcn_mfma_f32_16x16x32_bf16(aml, bwh[ct], a, 0, 0, 0);
        a = __builtin_amdgcn_mfma_f32_16x16x32_bf16(ahh, buh[ct], a, 0, 0, 0);
        a = __builtin_amdgcn_mfma_f32_16x16x32_bf16(ahh, bul[ct], a, 0, 0, 0);
        a = __builtin_amdgcn_mfma_f32_16x16x32_bf16(ahl, buh[ct], a, 0, 0, 0);
        acc[rt][ct] = a;
      }
    }
  }

  // ---- transition: f = sigmoid(z_f + bf); g = f*h overwrites h tile ----
  __syncthreads();  // all phase-A reads of hHi/hLo complete
  float fv[2][2][4], hvv[2][2][4];
#pragma unroll
  for (int rt = 0; rt < 2; ++rt)
#pragma unroll
    for (int ct = 0; ct < 2; ++ct) {
      int j = (2 * w + ct) * 16 + lj;
#pragma unroll
      for (int r = 0; r < 4; ++r) {
        int nl = rt * 16 + q * 4 + r;
        float z = acc[rt][ct][r] + bfj[ct];
        float f = sigmoid_f(z);
        int he = nl * LDST + j;
        float hval = (float)hHi[he] + (float)hLo[he];
        float g = f * hval;
        __bf16 ghi = (__bf16)g;
        hHi[he] = ghi;
        hLo[he] = (__bf16)(g - (float)ghi);
        fv[rt][ct][r] = f;
        hvv[rt][ct][r] = hval;
        acc[rt][ct][r] = 0.f;
      }
    }
  __syncthreads();

  // ---- phase B: z_h = m@Wh.T + g@Uh.T ----
#pragma unroll
  for (int kc = 0; kc < 128; kc += 32) {
    bf16x8 bwh[2], bwl[2], buh[2], bul[2];
#pragma unroll
    for (int ct = 0; ct < 2; ++ct) {
      int off = ((2 * w + ct) * 16 + lj) * 128 + kc + q * 8;
      bwh[ct] = *(const bf16x8*)&Whi[2 * 16384 + off];
      bwl[ct] = *(const bf16x8*)&Wlo[2 * 16384 + off];
      buh[ct] = *(const bf16x8*)&Whi[3 * 16384 + off];
      bul[ct] = *(const bf16x8*)&Wlo[3 * 16384 + off];
    }
#pragma unroll
    for (int rt = 0; rt < 2; ++rt) {
      int e0 = (rt * 16 + lj) * LDST + kc + q * 8;
      bf16x8 amh = *(const bf16x8*)&mHi[e0];
      bf16x8 aml = *(const bf16x8*)&mLo[e0];
      bf16x8 agh = *(const bf16x8*)&hHi[e0];
      bf16x8 agl = *(const bf16x8*)&hLo[e0];
#pragma unroll
      for (int ct = 0; ct < 2; ++ct) {
        f32x4 a = acc[rt][ct];
        a = __builtin_amdgcn_mfma_f32_16x16x32_bf16(amh, bwh[ct], a, 0, 0, 0);
        a = __builtin_amdgcn_mfma_f32_16x16x32_bf16(amh, bwl[ct], a, 0, 0, 0);
        a = __builtin_amdgcn_mfma_f32_16x16x32_bf16(aml, bwh[ct], a, 0, 0, 0);
        a = __builtin_amdgcn_mfma_f32_16x16x32_bf16(agh, buh[ct], a, 0, 0, 0);
        a = __builtin_amdgcn_mfma_f32_16x16x32_bf16(agh, bul[ct], a, 0, 0, 0);
        a = __builtin_amdgcn_mfma_f32_16x16x32_bf16(agl, buh[ct], a, 0, 0, 0);
        acc[rt][ct] = a;
      }
    }
  }

  // ---- epilogue: h = (1-f)*h + f*tanh(z_h + bh) ----
#pragma unroll
  for (int rt = 0; rt < 2; ++rt)
#pragma unroll
    for (int ct = 0; ct < 2; ++ct) {
      int j = (2 * w + ct) * 16 + lj;
#pragma unroll
      for (int r = 0; r < 4; ++r) {
        float T = tanh_f(acc[rt][ct][r] + bhj[ct]);
        float f = fv[rt][ct][r];
        float hn = (1.f - f) * hvv[rt][ct][r] + f * T;
        h[(nb + rt * 16 + q * 4 + r) * 128 + j] = hn;
      }
    }
}

// ---------------------------------------------------------------------------
// Whole Set2Set in ONE kernel, flash-style fused attention, unroll-2 streams.
// (round-0 version — the measured-best s2s at 114 us; split/last-finisher
// variants measured equal-or-worse, rounds 4 and 7.)
// ---------------------------------------------------------------------------
__global__ __launch_bounds__(1024) void k_s2s(const float* __restrict__ h,
                                              const int* __restrict__ batch,
                                              const float* __restrict__ w_ih,
                                              const float* __restrict__ w_hh,
                                              const float* __restrict__ b_ih,
                                              const float* __restrict__ b_hh,
                                              const float* __restrict__ Wp,
                                              const float* __restrict__ bp,
                                              float* __restrict__ out) {
  const int g = blockIdx.x, t = threadIdx.x;
  const int w = t >> 6, l = t & 63;
  const int half = l >> 5, li = l & 31;
  const int hw = 2 * w + half;           // stream id 0..31
  __shared__ float qs[256];              // q_star = [q | r]
  __shared__ float hl[128], cl[128];
  __shared__ float gates[512];
  __shared__ float redM[32], redS[32], scl[32];
  __shared__ float rPart[32][132];       // row stride 528 B (16B aligned)
  __shared__ float gInvS;
  __shared__ int bnd[2];

  if (t < 2) {
    int tgt = g + t;
    int lo = 0, hi = N_NODES;
    while (lo < hi) { int mid = (lo + hi) >> 1; if (batch[mid] < tgt) lo = mid + 1; else hi = mid; }
    bnd[t] = lo;
  }
  if (t < 256) qs[t] = 0.f;
  if (t < 128) { hl[t] = 0.f; cl[t] = 0.f; }
  __syncthreads();
  const int s0 = bnd[0], s1 = bnd[1];

  for (int step = 0; step < 3; ++step) {
    // ---- LSTM gates: [512] = q_star@w_ih.T + h_l@w_hh.T + biases ----
#pragma unroll 2
    for (int jt = w; jt < 512; jt += 16) {
      const float* wi = w_ih + jt * 256;
      const float* wh = w_hh + jt * 128;
      float s = qs[l] * wi[l] + qs[l+64] * wi[l+64]
              + qs[l+128] * wi[l+128] + qs[l+192] * wi[l+192]
              + hl[l] * wh[l] + hl[l+64] * wh[l+64];
#pragma unroll
      for (int o = 32; o > 0; o >>= 1) s += __shfl_xor(s, o, 64);
      if (l == 0) gates[jt] = s + b_ih[jt] + b_hh[jt];
    }
    __syncthreads();
    if (t < 128) {
      float gi = gates[t], gf = gates[128 + t], gg = gates[256 + t], go = gates[384 + t];
      float c = sigmoid_f(gf) * cl[t] + sigmoid_f(gi) * tanh_f(gg);
      float hh = sigmoid_f(go) * tanh_f(c);
      cl[t] = c;
      hl[t] = hh;
      qs[t] = hh;  // q part
    }
    __syncthreads();

    // ---- fused attention (online softmax, single pass, 2 nodes in flight) ----
    float mw = -INFINITY, sw = 0.f;
    float4 racc = {0.f, 0.f, 0.f, 0.f};
    const float4* h4 = (const float4*)h;
    const float q0 = qs[4*li], q1 = qs[4*li+1], q2 = qs[4*li+2], q3 = qs[4*li+3];
    int n = s0 + hw;
    for (; n + 32 < s1; n += 64) {
      float4 hv0 = h4[n * 32 + li];
      float4 hv1 = h4[(n + 32) * 32 + li];
      float v0 = hv0.x * q0 + hv0.y * q1 + hv0.z * q2 + hv0.w * q3;
      float v1 = hv1.x * q0 + hv1.y * q1 + hv1.z * q2 + hv1.w * q3;
#pragma unroll
      for (int o = 16; o > 0; o >>= 1) {
        v0 += __shfl_xor(v0, o, 64);
        v1 += __shfl_xor(v1, o, 64);
      }
      float nm = fmaxf(mw, fmaxf(v0, v1));
      float sc = __expf(mw - nm);
      float w0 = __expf(v0 - nm);
      float w1 = __expf(v1 - nm);
      sw = sw * sc + w0 + w1;
      racc.x = racc.x * sc + w0 * hv0.x + w1 * hv1.x;
      racc.y = racc.y * sc + w0 * hv0.y + w1 * hv1.y;
      racc.z = racc.z * sc + w0 * hv0.z + w1 * hv1.z;
      racc.w = racc.w * sc + w0 * hv0.w + w1 * hv1.w;
      mw = nm;
    }
    for (; n < s1; n += 32) {
      float4 hv = h4[n * 32 + li];
      float v = hv.x * q0 + hv.y * q1 + hv.z * q2 + hv.w * q3;
#pragma unroll
      for (int o = 16; o > 0; o >>= 1) v += __shfl_xor(v, o, 64);
      float nm = fmaxf(mw, v);
      float sc = __expf(mw - nm);
      float wg = __expf(v - nm);
      sw = sw * sc + wg;
      racc.x = racc.x * sc + wg * hv.x;
      racc.y = racc.y * sc + wg * hv.y;
      racc.z = racc.z * sc + wg * hv.z;
      racc.w = racc.w * sc + wg * hv.w;
      mw = nm;
    }
    if (li == 0) { redM[hw] = mw; redS[hw] = sw; }
    *(float4*)&rPart[hw][4 * li] = racc;
    __syncthreads();
    if (t == 0) {
      float M = -INFINITY;
      for (int i = 0; i < 32; ++i) M = fmaxf(M, redM[i]);
      float S = 0.f;
      for (int i = 0; i < 32; ++i) {
        float s_ = (redM[i] > -INFINITY && M > -INFINITY) ? __expf(redM[i] - M) : 0.f;
        scl[i] = s_;
        S += redS[i] * s_;
      }
      gInvS = (S > 0.f) ? __fdividef(1.f, S) : 0.f;
    }
    __syncthreads();
    if (t < 128) {
      float inv = gInvS;
      float r = 0.f;
#pragma unroll
      for (int i = 0; i < 32; ++i) r += rPart[i][t] * scl[i];
      qs[128 + t] = r * inv;
    }
    __syncthreads();
  }

  // ---- prediction: out[g] = <q_star, W_pred> + b ----
  __shared__ float pr[256];
  if (t < 256) pr[t] = qs[t] * Wp[t];
  __syncthreads();
  if (t < 128) pr[t] += pr[t + 128];
  __syncthreads();
  if (t < 64) {
    float s = pr[t] + pr[t + 64];
#pragma unroll
    for (int o = 32; o > 0; o >>= 1) s += __shfl_xor(s, o, 64);
    if (t == 0) out[g] = s + bp[0];
  }
}

// ---------------------------------------------------------------------------
extern "C" void kernel_launch(void* const* d_in, const int* in_sizes, int n_in,
                              void* d_out, int out_size, void* d_ws, size_t ws_size,
                              hipStream_t stream) {
  const float* x      = (const float*)d_in[0];
  const int*   ei     = (const int*)d_in[1];
  const int*   batch  = (const int*)d_in[2];
  const float* W_in   = (const float*)d_in[3];
  const float* b_in   = (const float*)d_in[4];
  const float* W_f    = (const float*)d_in[5];
  const float* U_f    = (const float*)d_in[6];
  const float* b_f    = (const float*)d_in[7];
  const float* W_h    = (const float*)d_in[8];
  const float* U_h    = (const float*)d_in[9];
  const float* b_h    = (const float*)d_in[10];
  const float* w_ih   = (const float*)d_in[11];
  const float* w_hh   = (const float*)d_in[12];
  const float* b_ih   = (const float*)d_in[13];
  const float* b_hh   = (const float*)d_in[14];
  const float* W_pred = (const float*)d_in[15];
  const float* b_pred = (const float*)d_in[16];
  float* out = (float*)d_out;

  char* ws = (char*)d_ws;
  float* h      = (float*)(ws);                    // 51,200,000 B
  float* m      = (float*)(ws + 51200000);         // 51,200,000 B
  int*   rowstart = (int*)(ws + 103063808);        //    400,016 B
  int*   srcSorted= (int*)(ws + 103463824);        //  2,560,000 B
  int*   bsum   = (int*)  (ws + 106023824);        //        112 B
  int*   boff   = (int*)  (ws + 106023936);        //        112 B
  // region at +102,400,000 (400,000 B): deg/cursor (CSR build) then Whi/Wlo
  int*    deg    = (int*)(ws + 102400000);
  int*    cursor = (int*)(ws + 102400000);
  __bf16* Whi    = (__bf16*)(ws + 102400000);      //    131,072 B
  __bf16* Wlo    = (__bf16*)(ws + 102531072);      //    131,072 B

  const int* src = ei;
  const int* dst = ei + N_EDGES;

  // ---- CSR build (once; reused by all 3 MPNN steps) ----
  hipMemsetAsync(deg, 0, N_NODES * 4, stream);
  k_hist<<<(N_EDGES + 255) / 256, 256, 0, stream>>>(dst, deg);
  k_scan_part<<<SCAN_NB, 256, 0, stream>>>(deg, bsum);
  k_scan_mid<<<1, 32, 0, stream>>>(bsum, boff, rowstart);
  k_scan_final<<<SCAN_NB, 256, 0, stream>>>(deg, boff, rowstart);
  hipMemcpyAsync(cursor, rowstart, N_NODES * 4, hipMemcpyDeviceToDevice, stream);
  k_fill<<<(N_EDGES + 255) / 256, 256, 0, stream>>>(src, dst, cursor, srcSorted);

  // ---- one-time weight bf16 hi/lo split (overwrites deg/cursor region) ----
  k_wsplit<<<256, 256, 0, stream>>>(W_f, U_f, W_h, U_h, Whi, Wlo);

  k_input<<<N_NODES / 32, 256, 0, stream>>>(x, W_in, b_in, h);

  // ---- MPNN: gather + in-place MGU (32-node tile, 4 blocks/CU) ----
  for (int step = 0; step < 3; ++step) {
    k_gather<<<(N_NODES + 7) / 8, 256, 0, stream>>>(h, rowstart, srcSorted, m);
    k_mgu<<<N_NODES / 32, 256, 0, stream>>>(h, m, Whi, Wlo, b_f, b_h);
  }

  // ---- entire Set2Set + prediction in one launch ----
  k_s2s<<<NGRAPH, 1024, 0, stream>>>(h, batch, w_ih, w_hh, b_ih, b_hh,
                                     W_pred, b_pred, out);
}